// Round 1
// baseline (468.128 us; speedup 1.0000x reference)
//
#include <hip/hip_runtime.h>
#include <cmath>

#define NB 4
#define NT 20
#define NC 128
#define ND 64
#define TD 1280   // T*D

// ---------------------------------------------------------------------------
// Kernel A: fu/fv projection.  fuv[(b*C+c)*256 + half*128 + k] =
//   sum_j h_flat[b,c,j] * W1[k, half*1280 + j],  h_flat[b,c,t*D+d]=h[b,t,c,d]
// Grid: 128 blocks = 64 (b,c-octet) x 2 (kk half).  Thread tile: 2c x 2kk.
// ---------------------------------------------------------------------------
__global__ __launch_bounds__(256) void k_fuv(
    const float* __restrict__ h, const float* __restrict__ W1,
    float* __restrict__ fuv) {
  int blk = blockIdx.x;
  int ct = blk >> 1;
  int kh = blk & 1;
  int b = ct >> 4;
  int c0 = (ct & 15) << 3;
  __shared__ float hrow[8][TD];   // 40 KB
  int t = threadIdx.x;
  for (int i = t; i < 8 * TD; i += 256) {
    int ci = i / TD;
    int j = i - ci * TD;
    int tt = j >> 6, d = j & 63;
    hrow[ci][j] = h[(((size_t)(b * NT + tt)) * NC + (c0 + ci)) * ND + d];
  }
  __syncthreads();
  int cg = t >> 6;                 // 0..3 (wave-uniform -> LDS broadcast)
  int cl0 = cg * 2;
  int kk = kh * 128 + ((t & 63) << 1);
  int kk1 = kk + 1;
  const float* w1a = W1 + (size_t)(kk & 127) * (2 * TD) + (kk >> 7) * TD;
  const float* w1b = W1 + (size_t)(kk1 & 127) * (2 * TD) + (kk1 >> 7) * TD;
  float acc00 = 0.f, acc01 = 0.f, acc10 = 0.f, acc11 = 0.f;
  for (int j = 0; j < TD; j += 4) {
    float4 wa = *(const float4*)(w1a + j);
    float4 wb = *(const float4*)(w1b + j);
    float4 xa = *(const float4*)(&hrow[cl0][j]);
    float4 xb = *(const float4*)(&hrow[cl0 + 1][j]);
    acc00 += wa.x * xa.x + wa.y * xa.y + wa.z * xa.z + wa.w * xa.w;
    acc01 += wb.x * xa.x + wb.y * xa.y + wb.z * xa.z + wb.w * xa.w;
    acc10 += wa.x * xb.x + wa.y * xb.y + wa.z * xb.z + wa.w * xb.w;
    acc11 += wb.x * xb.x + wb.y * xb.y + wb.z * xb.z + wb.w * xb.w;
  }
  size_t base0 = ((size_t)(b * NC + c0 + cl0)) * 256 + kk;
  size_t base1 = ((size_t)(b * NC + c0 + cl0 + 1)) * 256 + kk;
  fuv[base0] = acc00; fuv[base0 + 1] = acc01;
  fuv[base1] = acc10; fuv[base1 + 1] = acc11;
}

// ---------------------------------------------------------------------------
// Kernel B: pairwise MLP -> w, written TRANSPOSED wT[b][v][u].
// Grid: 4096 blocks = b(4) x u(128) x vchunk(8, 16 v's each).  256 thr.
// ---------------------------------------------------------------------------
__global__ __launch_bounds__(256) void k_pair(
    const float* __restrict__ fuv, const float* __restrict__ b1,
    const float* __restrict__ W2, const float* __restrict__ b2,
    const float* __restrict__ W3, const float* __restrict__ b3,
    const float* __restrict__ W4, const float* __restrict__ b4,
    const float* __restrict__ A_a, float* __restrict__ wT) {
  int blk = blockIdx.x;
  int b = blk >> 10;
  int u = (blk >> 3) & 127;
  int v0 = (blk & 7) << 4;
  __shared__ float x1[16][132];   // +4 pad: 2-way (free) bank aliasing
  __shared__ float y[16][36];     // +4 pad
  __shared__ float red[16][17];
  int t = threadIdx.x;
  const float* fub = fuv + ((size_t)(b * NC + u)) * 256;
  for (int i = t; i < 2048; i += 256) {
    int p = i >> 7, k = i & 127;
    float val = fub[k] + fuv[((size_t)(b * NC + v0 + p)) * 256 + 128 + k] + b1[k];
    x1[p][k] = val > 0.f ? val : 0.f;
  }
  __syncthreads();
  int p = t & 15;
  int g = t >> 4;                 // 0..15
  int j0 = g * 4;                 // layer-3 output ownership: 4 j's/thread
  float x3acc[4] = {0.f, 0.f, 0.f, 0.f};
  for (int mc = 0; mc < 256; mc += 32) {
    // layer 2: thread computes y[p][g] and y[p][g+16], sharing x1 loads
    int m0 = mc + g;
    const float* w2a = W2 + (size_t)m0 * 128;
    const float* w2b = w2a + 16 * 128;
    float a0 = b2[m0], a1 = b2[m0 + 16];
    for (int k = 0; k < 128; k += 4) {
      float4 xv = *(const float4*)(&x1[p][k]);
      float4 wa = *(const float4*)(w2a + k);
      float4 wb = *(const float4*)(w2b + k);
      a0 += wa.x * xv.x + wa.y * xv.y + wa.z * xv.z + wa.w * xv.w;
      a1 += wb.x * xv.x + wb.y * xv.y + wb.z * xv.z + wb.w * xv.w;
    }
    y[p][g] = a0 > 0.f ? a0 : 0.f;
    y[p][g + 16] = a1 > 0.f ? a1 : 0.f;
    __syncthreads();
    // layer 3 partial accumulation (registers), y vector shared across jj
    for (int mm = 0; mm < 32; mm += 4) {
      float4 yv = *(const float4*)(&y[p][mm]);
#pragma unroll
      for (int jj = 0; jj < 4; jj++) {
        float4 w3 = *(const float4*)(W3 + (size_t)(j0 + jj) * 256 + mc + mm);
        x3acc[jj] += w3.x * yv.x + w3.y * yv.y + w3.z * yv.z + w3.w * yv.w;
      }
    }
    __syncthreads();
  }
  // layer 4 + sigmoid + A_a scale
  float partial = 0.f;
#pragma unroll
  for (int jj = 0; jj < 4; jj++) {
    float xv = x3acc[jj] + b3[j0 + jj];
    xv = xv > 0.f ? xv : 0.f;
    partial += W4[j0 + jj] * xv;
  }
  red[p][g] = partial;
  __syncthreads();
  if (t < 16) {
    float s = b4[0];
#pragma unroll
    for (int i = 0; i < 16; i++) s += red[t][i];
    float sg = 1.f / (1.f + expf(-s));
    int v = v0 + t;
    wT[((size_t)(b * NC + v)) * NC + u] = sg * A_a[u * NC + v];
  }
}

// ---------------------------------------------------------------------------
// Kernel C: a/m einsums + output projections + beta combine, fused.
// Grid: 320 blocks = b(4) x t(20) x vchunk(4, 32 v's).  256 thr = 4v x 64d.
// ---------------------------------------------------------------------------
__global__ __launch_bounds__(256) void k_out(
    const float* __restrict__ h, const float* __restrict__ wT,
    const float* __restrict__ A_m, const float* __restrict__ W_add,
    const float* __restrict__ b_add, const float* __restrict__ W_mod,
    const float* __restrict__ b_mod, const float* __restrict__ beta1p,
    const float* __restrict__ beta2p, const float* __restrict__ beta3p,
    float* __restrict__ out) {
  int blk = blockIdx.x;
  int b = blk / 80;
  int rest = blk - b * 80;
  int tt = rest >> 2;
  int v0 = (rest & 3) << 5;
  __shared__ float hs[NC][ND];    // 32 KB, reads broadcast or stride-1
  __shared__ float WaT[ND][65];   // transposed + padded -> conflict-free
  __shared__ float WmT[ND][65];
  __shared__ float wcol[4][NC];
  __shared__ float amcol[4][NC];
  __shared__ float apre[4][ND];
  __shared__ float mpre[4][ND];
  int t = threadIdx.x;
  const float* hb = h + ((size_t)(b * NT + tt)) * NC * ND;
  for (int i = t; i < NC * ND; i += 256) hs[i >> 6][i & 63] = hb[i];
  for (int i = t; i < ND * ND; i += 256) {
    int d = i >> 6, e = i & 63;
    WaT[e][d] = W_add[i];
    WmT[e][d] = W_mod[i];
  }
  float bb1 = beta1p[0], bb2 = beta2p[0], bb3 = beta3p[0];
  __syncthreads();
  int vi = t >> 6, d = t & 63;
  for (int vo = 0; vo < 8; vo++) {
    for (int i = t; i < 512; i += 256) {
      int vv = i >> 7, uu = i & 127;
      int v = v0 + vo * 4 + vv;
      wcol[vv][uu] = wT[((size_t)(b * NC + v)) * NC + uu];
      amcol[vv][uu] = A_m[uu * NC + v];
    }
    __syncthreads();
    int v = v0 + vo * 4 + vi;
    float asum = 0.f, msum = 0.f;
    for (int uu = 0; uu < NC; uu++) {
      float hv = hs[uu][d];              // stride-1 across lanes
      asum += wcol[vi][uu] * hv;         // broadcast
      msum += amcol[vi][uu] * hv;        // broadcast
    }
    apre[vi][d] = asum;
    mpre[vi][d] = msum * hs[v][d];
    __syncthreads();
    float accA = b_add[d], accM = b_mod[d];
    for (int e = 0; e < ND; e++) {
      accA += WaT[e][d] * apre[vi][e];   // conflict-free / broadcast
      accM += WmT[e][d] * mpre[vi][e];
    }
    out[(((size_t)(b * NT + tt)) * NC + v) * ND + d] =
        bb1 * hs[v][d] + bb2 * accA + bb3 * accM;
    __syncthreads();
  }
}

// ---------------------------------------------------------------------------
extern "C" void kernel_launch(void* const* d_in, const int* in_sizes, int n_in,
                              void* d_out, int out_size, void* d_ws, size_t ws_size,
                              hipStream_t stream) {
  const float* h     = (const float*)d_in[0];
  const float* W1    = (const float*)d_in[1];
  const float* b1    = (const float*)d_in[2];
  const float* W2    = (const float*)d_in[3];
  const float* b2    = (const float*)d_in[4];
  const float* W3    = (const float*)d_in[5];
  const float* b3    = (const float*)d_in[6];
  const float* W4    = (const float*)d_in[7];
  const float* b4    = (const float*)d_in[8];
  const float* A_a   = (const float*)d_in[9];
  const float* A_m   = (const float*)d_in[10];
  const float* W_add = (const float*)d_in[11];
  const float* b_add = (const float*)d_in[12];
  const float* W_mod = (const float*)d_in[13];
  const float* b_mod = (const float*)d_in[14];
  const float* beta1 = (const float*)d_in[15];
  const float* beta2 = (const float*)d_in[16];
  const float* beta3 = (const float*)d_in[17];
  float* out = (float*)d_out;

  float* fuv = (float*)d_ws;                       // 4*128*256 f32 = 512 KB
  float* wT  = fuv + (size_t)NB * NC * 256;        // 4*128*128 f32 = 256 KB

  k_fuv<<<128, 256, 0, stream>>>(h, W1, fuv);
  k_pair<<<4096, 256, 0, stream>>>(fuv, b1, W2, b2, W3, b3, W4, b4, A_a, wT);
  k_out<<<320, 256, 0, stream>>>(h, wT, A_m, W_add, b_add, W_mod, b_mod,
                                 beta1, beta2, beta3, out);
}

// Round 2
// 155.843 us; speedup vs baseline: 3.0039x; 3.0039x over previous
//
#include <hip/hip_runtime.h>
#include <cmath>

#define NB 4
#define NT 20
#define NC 128
#define ND 64
#define TD 1280   // T*D

typedef short short8 __attribute__((ext_vector_type(8)));
typedef float f32x4 __attribute__((ext_vector_type(4)));

static __device__ __forceinline__ unsigned short f2bf(float f) {
  union { float f; unsigned int u; } v; v.f = f;
  unsigned int r = v.u + 0x7FFFu + ((v.u >> 16) & 1u);
  return (unsigned short)(r >> 16);
}

// ---------------------------------------------------------------------------
// Convert W2 (256x128) and W3 (64x256) to bf16 once per launch.
// ---------------------------------------------------------------------------
__global__ __launch_bounds__(256) void k_conv(
    const float* __restrict__ W2, const float* __restrict__ W3,
    unsigned short* __restrict__ W2bf, unsigned short* __restrict__ W3bf) {
  int i = blockIdx.x * 256 + threadIdx.x;
  if (i < 256 * 128) W2bf[i] = f2bf(W2[i]);
  if (i < 64 * 256) W3bf[i] = f2bf(W3[i]);
}

// ---------------------------------------------------------------------------
// Kernel A: fu/fv projection (f32 VALU).  256 blocks = 128 (b,c-quad) x 2 kh.
// ---------------------------------------------------------------------------
__global__ __launch_bounds__(256) void k_fuv(
    const float* __restrict__ h, const float* __restrict__ W1,
    float* __restrict__ fuv) {
  int blk = blockIdx.x;
  int ct = blk >> 1;
  int kh = blk & 1;
  int b = ct >> 5;
  int c0 = (ct & 31) << 2;
  __shared__ float hrow[4][TD];   // 20 KB
  int t = threadIdx.x;
  for (int i = t; i < 4 * TD; i += 256) {
    int ci = i / TD;
    int j = i - ci * TD;
    int tt = j >> 6, d = j & 63;
    hrow[ci][j] = h[(((size_t)(b * NT + tt)) * NC + (c0 + ci)) * ND + d];
  }
  __syncthreads();
  int cl = t >> 6;                 // 0..3 (wave-uniform -> LDS broadcast)
  int kk = kh * 128 + ((t & 63) << 1);
  int kk1 = kk + 1;
  const float* w1a = W1 + (size_t)(kk & 127) * (2 * TD) + (kk >> 7) * TD;
  const float* w1b = W1 + (size_t)(kk1 & 127) * (2 * TD) + (kk1 >> 7) * TD;
  float acc0 = 0.f, acc1 = 0.f;
  for (int j = 0; j < TD; j += 4) {
    float4 wa = *(const float4*)(w1a + j);
    float4 wb = *(const float4*)(w1b + j);
    float4 xa = *(const float4*)(&hrow[cl][j]);
    acc0 += wa.x * xa.x + wa.y * xa.y + wa.z * xa.z + wa.w * xa.w;
    acc1 += wb.x * xa.x + wb.y * xa.y + wb.z * xa.z + wb.w * xa.w;
  }
  size_t base = ((size_t)(b * NC + c0 + cl)) * 256 + kk;
  fuv[base] = acc0; fuv[base + 1] = acc1;
}

// ---------------------------------------------------------------------------
// Kernel B (MFMA): pairwise MLP -> wT[b][v][u].
// Grid 512 = b(4) x u(128).  4 waves; wave w owns v in [32w, 32w+32).
// X1 (128x128 bf16) in LDS, XOR-swizzled (256B rows = 32-way conflict case).
// Y staged per-wave (32x64 bf16, private -> no barriers in main loop).
// Z accumulated in MFMA acc regs across 4 m-chunks.
// ---------------------------------------------------------------------------
__global__ __launch_bounds__(256) void k_pair(
    const float* __restrict__ fuv, const float* __restrict__ b1,
    const unsigned short* __restrict__ W2bf, const float* __restrict__ b2,
    const unsigned short* __restrict__ W3bf, const float* __restrict__ b3,
    const float* __restrict__ W4, const float* __restrict__ b4,
    const float* __restrict__ A_a, float* __restrict__ wT) {
  int blk = blockIdx.x;
  int b = blk >> 7;
  int u = blk & 127;
  __shared__ char x1raw[32768];        // [128 v][128 k] bf16, swizzled
  __shared__ char ycraw[4][8192];      // per-wave [32 v][64 m] bf16, swizzled
  int t = threadIdx.x;
  int lane = t & 63;
  int w = t >> 6;
  const float* fub = fuv + ((size_t)(b * NC + u)) * 256;

  // ---- build X1 = relu(fu[u] + fv[v] + b1), f32 math then bf16 pack ----
  {
    int v = t >> 1;
    int kh2 = (t & 1) << 6;            // 0 or 64
    const float* fvrow = fuv + ((size_t)(b * NC + v)) * 256 + 128 + kh2;
    const float* fur = fub + kh2;
    const float* b1r = b1 + kh2;
    int sw = (v & 7) << 4;
    int rowbase = v * 256 + kh2 * 2;
    for (int kc = 0; kc < 64; kc += 8) {
      float e[8];
#pragma unroll
      for (int i2 = 0; i2 < 8; i2++) {
        float val = fur[kc + i2] + fvrow[kc + i2] + b1r[kc + i2];
        e[i2] = val > 0.f ? val : 0.f;
      }
      unsigned int pw[4];
#pragma unroll
      for (int i2 = 0; i2 < 4; i2++)
        pw[i2] = (unsigned int)f2bf(e[2 * i2]) |
                 ((unsigned int)f2bf(e[2 * i2 + 1]) << 16);
      *(uint4*)(x1raw + ((rowbase + kc * 2) ^ sw)) =
          make_uint4(pw[0], pw[1], pw[2], pw[3]);
    }
  }
  __syncthreads();

  int v0w = w * 32;
  int lr = lane & 15;                  // row/col within 16-tile
  int lhi = lane >> 4;                 // 0..3 (k-slice group)
  int sw = (lr & 7) << 4;
  char* ycb = ycraw[w];

  f32x4 zacc[2][4];
#pragma unroll
  for (int q = 0; q < 2; q++)
#pragma unroll
    for (int n = 0; n < 4; n++) zacc[q][n] = (f32x4){0.f, 0.f, 0.f, 0.f};

  for (int mc = 0; mc < 256; mc += 64) {
    // --- GEMM1: Yc[32v][64m] = X1 @ W2[mc:mc+64]^T ---
    f32x4 yac[2][4];
#pragma unroll
    for (int q = 0; q < 2; q++)
#pragma unroll
      for (int n = 0; n < 4; n++) yac[q][n] = (f32x4){0.f, 0.f, 0.f, 0.f};
    float b2v[4];
#pragma unroll
    for (int n = 0; n < 4; n++) b2v[n] = b2[mc + 16 * n + lr];

#pragma unroll
    for (int ks = 0; ks < 4; ks++) {
      int kb = ks * 32 + lhi * 8;
      int r0 = (v0w + lr) * 256 + kb * 2;
      short8 a0 = *(const short8*)(x1raw + (r0 ^ sw));
      short8 a1 = *(const short8*)(x1raw + ((r0 + 16 * 256) ^ sw));
#pragma unroll
      for (int n = 0; n < 4; n++) {
        const unsigned short* wp = W2bf + (size_t)(mc + 16 * n + lr) * 128 + kb;
        short8 bfv = *(const short8*)wp;
        yac[0][n] = __builtin_amdgcn_mfma_f32_16x16x32_bf16(a0, bfv, yac[0][n], 0, 0, 0);
        yac[1][n] = __builtin_amdgcn_mfma_f32_16x16x32_bf16(a1, bfv, yac[1][n], 0, 0, 0);
      }
    }
    // --- bias + relu + bf16 store into private yc ---
#pragma unroll
    for (int q = 0; q < 2; q++)
#pragma unroll
      for (int n = 0; n < 4; n++) {
        int ml = 16 * n + lr;
#pragma unroll
        for (int r = 0; r < 4; r++) {
          int vl = 16 * q + lhi * 4 + r;
          float yv = yac[q][n][r] + b2v[n];
          yv = yv > 0.f ? yv : 0.f;
          *(unsigned short*)(ycb + ((vl * 128 + ml * 2) ^ ((vl & 7) << 4))) = f2bf(yv);
        }
      }
    // --- GEMM2 partial: Z += Yc @ W3[:, mc:mc+64]^T (same-wave, waitcnt only) ---
#pragma unroll
    for (int ks = 0; ks < 2; ks++) {
      int kb = ks * 32 + lhi * 8;
      short8 ya0 = *(const short8*)(ycb + ((lr * 128 + kb * 2) ^ sw));
      short8 ya1 = *(const short8*)(ycb + (((16 + lr) * 128 + kb * 2) ^ sw));
#pragma unroll
      for (int n = 0; n < 4; n++) {
        const unsigned short* wp = W3bf + (size_t)(16 * n + lr) * 256 + mc + kb;
        short8 w3v = *(const short8*)wp;
        zacc[0][n] = __builtin_amdgcn_mfma_f32_16x16x32_bf16(ya0, w3v, zacc[0][n], 0, 0, 0);
        zacc[1][n] = __builtin_amdgcn_mfma_f32_16x16x32_bf16(ya1, w3v, zacc[1][n], 0, 0, 0);
      }
    }
  }

  // ---- layer3 bias/relu + layer4 dot + 16-lane butterfly + sigmoid ----
  float sp[2][4];
#pragma unroll
  for (int q = 0; q < 2; q++)
#pragma unroll
    for (int r = 0; r < 4; r++) sp[q][r] = 0.f;
#pragma unroll
  for (int n = 0; n < 4; n++) {
    int j = 16 * n + lr;
    float b3v = b3[j], w4v = W4[j];
#pragma unroll
    for (int q = 0; q < 2; q++)
#pragma unroll
      for (int r = 0; r < 4; r++) {
        float z = zacc[q][n][r] + b3v;
        z = z > 0.f ? z : 0.f;
        sp[q][r] += w4v * z;
      }
  }
#pragma unroll
  for (int mask = 1; mask <= 8; mask <<= 1)
#pragma unroll
    for (int q = 0; q < 2; q++)
#pragma unroll
      for (int r = 0; r < 4; r++)
        sp[q][r] += __shfl_xor(sp[q][r], mask, 64);
  float bb4 = b4[0];
  if (lr == 0) {
#pragma unroll
    for (int q = 0; q < 2; q++)
#pragma unroll
      for (int r = 0; r < 4; r++) {
        int v = v0w + 16 * q + lhi * 4 + r;
        float s = 1.f / (1.f + expf(-(sp[q][r] + bb4)));
        wT[((size_t)(b * NC + v)) * NC + u] = s * A_a[u * NC + v];
      }
  }
}

// ---------------------------------------------------------------------------
// Kernel C: a/m einsums + output projections + beta combine, fused.
// ---------------------------------------------------------------------------
__global__ __launch_bounds__(256) void k_out(
    const float* __restrict__ h, const float* __restrict__ wT,
    const float* __restrict__ A_m, const float* __restrict__ W_add,
    const float* __restrict__ b_add, const float* __restrict__ W_mod,
    const float* __restrict__ b_mod, const float* __restrict__ beta1p,
    const float* __restrict__ beta2p, const float* __restrict__ beta3p,
    float* __restrict__ out) {
  int blk = blockIdx.x;
  int b = blk / 80;
  int rest = blk - b * 80;
  int tt = rest >> 2;
  int v0 = (rest & 3) << 5;
  __shared__ float hs[NC][ND];
  __shared__ float WaT[ND][65];
  __shared__ float WmT[ND][65];
  __shared__ float wcol[4][NC];
  __shared__ float amcol[4][NC];
  __shared__ float apre[4][ND];
  __shared__ float mpre[4][ND];
  int t = threadIdx.x;
  const float* hb = h + ((size_t)(b * NT + tt)) * NC * ND;
  for (int i = t; i < NC * ND; i += 256) hs[i >> 6][i & 63] = hb[i];
  for (int i = t; i < ND * ND; i += 256) {
    int d = i >> 6, e = i & 63;
    WaT[e][d] = W_add[i];
    WmT[e][d] = W_mod[i];
  }
  float bb1 = beta1p[0], bb2 = beta2p[0], bb3 = beta3p[0];
  __syncthreads();
  int vi = t >> 6, d = t & 63;
  for (int vo = 0; vo < 8; vo++) {
    for (int i = t; i < 512; i += 256) {
      int vv = i >> 7, uu = i & 127;
      int v = v0 + vo * 4 + vv;
      wcol[vv][uu] = wT[((size_t)(b * NC + v)) * NC + uu];
      amcol[vv][uu] = A_m[uu * NC + v];
    }
    __syncthreads();
    int v = v0 + vo * 4 + vi;
    float asum = 0.f, msum = 0.f;
    for (int uu = 0; uu < NC; uu++) {
      float hv = hs[uu][d];
      asum += wcol[vi][uu] * hv;
      msum += amcol[vi][uu] * hv;
    }
    apre[vi][d] = asum;
    mpre[vi][d] = msum * hs[v][d];
    __syncthreads();
    float accA = b_add[d], accM = b_mod[d];
    for (int e = 0; e < ND; e++) {
      accA += WaT[e][d] * apre[vi][e];
      accM += WmT[e][d] * mpre[vi][e];
    }
    out[(((size_t)(b * NT + tt)) * NC + v) * ND + d] =
        bb1 * hs[v][d] + bb2 * accA + bb3 * accM;
    __syncthreads();
  }
}

// ---------------------------------------------------------------------------
extern "C" void kernel_launch(void* const* d_in, const int* in_sizes, int n_in,
                              void* d_out, int out_size, void* d_ws, size_t ws_size,
                              hipStream_t stream) {
  const float* h     = (const float*)d_in[0];
  const float* W1    = (const float*)d_in[1];
  const float* b1    = (const float*)d_in[2];
  const float* W2    = (const float*)d_in[3];
  const float* b2    = (const float*)d_in[4];
  const float* W3    = (const float*)d_in[5];
  const float* b3    = (const float*)d_in[6];
  const float* W4    = (const float*)d_in[7];
  const float* b4    = (const float*)d_in[8];
  const float* A_a   = (const float*)d_in[9];
  const float* A_m   = (const float*)d_in[10];
  const float* W_add = (const float*)d_in[11];
  const float* b_add = (const float*)d_in[12];
  const float* W_mod = (const float*)d_in[13];
  const float* b_mod = (const float*)d_in[14];
  const float* beta1 = (const float*)d_in[15];
  const float* beta2 = (const float*)d_in[16];
  const float* beta3 = (const float*)d_in[17];
  float* out = (float*)d_out;

  float* fuv = (float*)d_ws;                        // 4*128*256 f32 = 512 KB
  float* wT  = fuv + (size_t)NB * NC * 256;         // 4*128*128 f32 = 256 KB
  unsigned short* W2bf = (unsigned short*)(wT + (size_t)NB * NC * NC); // 64 KB
  unsigned short* W3bf = W2bf + 256 * 128;          // 32 KB

  k_conv<<<128, 256, 0, stream>>>(W2, W3, W2bf, W3bf);
  k_fuv<<<256, 256, 0, stream>>>(h, W1, fuv);
  k_pair<<<512, 256, 0, stream>>>(fuv, b1, W2bf, b2, W3bf, b3, W4, b4, A_a, wT);
  k_out<<<320, 256, 0, stream>>>(h, wT, A_m, W_add, b_add, W_mod, b_mod,
                                 beta1, beta2, beta3, out);
}

// Round 3
// 91.398 us; speedup vs baseline: 5.1219x; 1.7051x over previous
//
#include <hip/hip_runtime.h>
#include <cmath>

#define NB 4
#define NT 20
#define NC 128
#define ND 64
#define TD 1280   // T*D

typedef short short8 __attribute__((ext_vector_type(8)));
typedef float f32x4 __attribute__((ext_vector_type(4)));

static __device__ __forceinline__ unsigned short f2bf(float f) {
  union { float f; unsigned int u; } v; v.f = f;
  unsigned int r = v.u + 0x7FFFu + ((v.u >> 16) & 1u);
  return (unsigned short)(r >> 16);
}

static __device__ __forceinline__ void conv16(const float* __restrict__ s,
                                              unsigned short* __restrict__ d) {
#pragma unroll
  for (int q = 0; q < 2; q++) {
    float4 f0 = *(const float4*)(s + q * 8);
    float4 f1 = *(const float4*)(s + q * 8 + 4);
    uint4 o;
    o.x = (unsigned)f2bf(f0.x) | ((unsigned)f2bf(f0.y) << 16);
    o.y = (unsigned)f2bf(f0.z) | ((unsigned)f2bf(f0.w) << 16);
    o.z = (unsigned)f2bf(f1.x) | ((unsigned)f2bf(f1.y) << 16);
    o.w = (unsigned)f2bf(f1.z) | ((unsigned)f2bf(f1.w) << 16);
    *(uint4*)(d + q * 8) = o;
  }
}

// ---------------------------------------------------------------------------
// Conversions: hbf (transposed to h_flat [b*C+c][t*D+d]), W1bf, W2bf, W3bf.
// Grid 252 blocks x 256 thr, 16 elems/thread.
// ---------------------------------------------------------------------------
__global__ __launch_bounds__(256) void k_conv(
    const float* __restrict__ h, const float* __restrict__ W1,
    const float* __restrict__ W2, const float* __restrict__ W3,
    unsigned short* __restrict__ hbf, unsigned short* __restrict__ W1bf,
    unsigned short* __restrict__ W2bf, unsigned short* __restrict__ W3bf) {
  int blk = blockIdx.x, tid = threadIdx.x;
  if (blk < 160) {                     // h transpose: 80 (b,t) x 8192 elems
    int bt = blk >> 1;
    int j = ((blk & 1) << 12) + tid * 16;
    int b = bt / 20, t5 = bt - b * 20;
    int c = j >> 6, d0 = j & 63;
    conv16(h + (size_t)bt * 8192 + j,
           hbf + ((size_t)(b * NC + c)) * TD + t5 * 64 + d0);
  } else if (blk < 240) {              // W1: 327680 elems
    size_t i = (size_t)(blk - 160) * 4096 + tid * 16;
    conv16(W1 + i, W1bf + i);
  } else if (blk < 248) {              // W2: 32768 elems
    size_t i = (size_t)(blk - 240) * 4096 + tid * 16;
    conv16(W2 + i, W2bf + i);
  } else {                             // W3: 16384 elems
    size_t i = (size_t)(blk - 248) * 4096 + tid * 16;
    conv16(W3 + i, W3bf + i);
  }
}

// ---------------------------------------------------------------------------
// Kernel A (MFMA): fuv = h_flat @ [W1u|W1v]^T.  M=512, N=256, K=1280.
// Grid 512 = 16 Mtiles(32) x 4 Ntiles(64) x 8 Ksplit(160).  128 thr = 2 waves.
// No LDS: A and B fragments are direct per-lane 16B L2 loads.
// ---------------------------------------------------------------------------
__global__ __launch_bounds__(128) void k_fuv_mfma(
    const unsigned short* __restrict__ hbf,
    const unsigned short* __restrict__ W1bf,
    float* __restrict__ part) {
  int blk = blockIdx.x;
  int mtile = blk & 15;
  int ntile = (blk >> 4) & 3;
  int ks = blk >> 6;
  int t = threadIdx.x;
  int lane = t & 63;
  int w = t >> 6;
  int lr = lane & 15, lhi = lane >> 4;
  int kc0 = ks * 160;
  int row = mtile * 32 + w * 16 + lr;
  const unsigned short* ap = hbf + (size_t)row * TD + kc0 + lhi * 8;
  const unsigned short* bp[4];
#pragma unroll
  for (int nf = 0; nf < 4; nf++) {
    int n = ntile * 64 + nf * 16 + lr;
    bp[nf] = W1bf + (size_t)(n & 127) * (2 * TD) + (n >> 7) * TD + kc0 + lhi * 8;
  }
  f32x4 acc[4];
#pragma unroll
  for (int nf = 0; nf < 4; nf++) acc[nf] = (f32x4){0.f, 0.f, 0.f, 0.f};
#pragma unroll
  for (int kb = 0; kb < 160; kb += 32) {
    short8 a = *(const short8*)(ap + kb);
#pragma unroll
    for (int nf = 0; nf < 4; nf++) {
      short8 bv = *(const short8*)(bp[nf] + kb);
      acc[nf] = __builtin_amdgcn_mfma_f32_16x16x32_bf16(a, bv, acc[nf], 0, 0, 0);
    }
  }
  float* pout = part + (size_t)ks * (512 * 256);
  int m0 = mtile * 32 + w * 16 + lhi * 4;
#pragma unroll
  for (int nf = 0; nf < 4; nf++)
#pragma unroll
    for (int r = 0; r < 4; r++)
      pout[(size_t)(m0 + r) * 256 + ntile * 64 + nf * 16 + lr] = acc[nf][r];
}

// ---------------------------------------------------------------------------
// Reduce split-K partials: fuv = sum over 8.  Grid 128 x 256, float4/thread.
// ---------------------------------------------------------------------------
__global__ __launch_bounds__(256) void k_fred(
    const float* __restrict__ part, float* __restrict__ fuv) {
  int i = blockIdx.x * 256 + threadIdx.x;
  float4 s = ((const float4*)part)[i];
#pragma unroll
  for (int p = 1; p < 8; p++) {
    float4 v = ((const float4*)part)[i + p * 32768];
    s.x += v.x; s.y += v.y; s.z += v.z; s.w += v.w;
  }
  ((float4*)fuv)[i] = s;
}

// ---------------------------------------------------------------------------
// Kernel B (MFMA): pairwise MLP -> wT[b][v][u].  (unchanged from R2)
// ---------------------------------------------------------------------------
__global__ __launch_bounds__(256) void k_pair(
    const float* __restrict__ fuv, const float* __restrict__ b1,
    const unsigned short* __restrict__ W2bf, const float* __restrict__ b2,
    const unsigned short* __restrict__ W3bf, const float* __restrict__ b3,
    const float* __restrict__ W4, const float* __restrict__ b4,
    const float* __restrict__ A_a, float* __restrict__ wT) {
  int blk = blockIdx.x;
  int b = blk >> 7;
  int u = blk & 127;
  __shared__ char x1raw[32768];        // [128 v][128 k] bf16, swizzled
  __shared__ char ycraw[4][8192];      // per-wave [32 v][64 m] bf16, swizzled
  int t = threadIdx.x;
  int lane = t & 63;
  int w = t >> 6;
  const float* fub = fuv + ((size_t)(b * NC + u)) * 256;

  {
    int v = t >> 1;
    int kh2 = (t & 1) << 6;
    const float* fvrow = fuv + ((size_t)(b * NC + v)) * 256 + 128 + kh2;
    const float* fur = fub + kh2;
    const float* b1r = b1 + kh2;
    int sw = (v & 7) << 4;
    int rowbase = v * 256 + kh2 * 2;
    for (int kc = 0; kc < 64; kc += 8) {
      float e[8];
#pragma unroll
      for (int i2 = 0; i2 < 8; i2++) {
        float val = fur[kc + i2] + fvrow[kc + i2] + b1r[kc + i2];
        e[i2] = val > 0.f ? val : 0.f;
      }
      unsigned int pw[4];
#pragma unroll
      for (int i2 = 0; i2 < 4; i2++)
        pw[i2] = (unsigned int)f2bf(e[2 * i2]) |
                 ((unsigned int)f2bf(e[2 * i2 + 1]) << 16);
      *(uint4*)(x1raw + ((rowbase + kc * 2) ^ sw)) =
          make_uint4(pw[0], pw[1], pw[2], pw[3]);
    }
  }
  __syncthreads();

  int v0w = w * 32;
  int lr = lane & 15;
  int lhi = lane >> 4;
  int sw = (lr & 7) << 4;
  char* ycb = ycraw[w];

  f32x4 zacc[2][4];
#pragma unroll
  for (int q = 0; q < 2; q++)
#pragma unroll
    for (int n = 0; n < 4; n++) zacc[q][n] = (f32x4){0.f, 0.f, 0.f, 0.f};

  for (int mc = 0; mc < 256; mc += 64) {
    f32x4 yac[2][4];
#pragma unroll
    for (int q = 0; q < 2; q++)
#pragma unroll
      for (int n = 0; n < 4; n++) yac[q][n] = (f32x4){0.f, 0.f, 0.f, 0.f};
    float b2v[4];
#pragma unroll
    for (int n = 0; n < 4; n++) b2v[n] = b2[mc + 16 * n + lr];

#pragma unroll
    for (int ks = 0; ks < 4; ks++) {
      int kb = ks * 32 + lhi * 8;
      int r0 = (v0w + lr) * 256 + kb * 2;
      short8 a0 = *(const short8*)(x1raw + (r0 ^ sw));
      short8 a1 = *(const short8*)(x1raw + ((r0 + 16 * 256) ^ sw));
#pragma unroll
      for (int n = 0; n < 4; n++) {
        const unsigned short* wp = W2bf + (size_t)(mc + 16 * n + lr) * 128 + kb;
        short8 bfv = *(const short8*)wp;
        yac[0][n] = __builtin_amdgcn_mfma_f32_16x16x32_bf16(a0, bfv, yac[0][n], 0, 0, 0);
        yac[1][n] = __builtin_amdgcn_mfma_f32_16x16x32_bf16(a1, bfv, yac[1][n], 0, 0, 0);
      }
    }
#pragma unroll
    for (int q = 0; q < 2; q++)
#pragma unroll
      for (int n = 0; n < 4; n++) {
        int ml = 16 * n + lr;
#pragma unroll
        for (int r = 0; r < 4; r++) {
          int vl = 16 * q + lhi * 4 + r;
          float yv = yac[q][n][r] + b2v[n];
          yv = yv > 0.f ? yv : 0.f;
          *(unsigned short*)(ycb + ((vl * 128 + ml * 2) ^ ((vl & 7) << 4))) = f2bf(yv);
        }
      }
#pragma unroll
    for (int ks = 0; ks < 2; ks++) {
      int kb = ks * 32 + lhi * 8;
      short8 ya0 = *(const short8*)(ycb + ((lr * 128 + kb * 2) ^ sw));
      short8 ya1 = *(const short8*)(ycb + (((16 + lr) * 128 + kb * 2) ^ sw));
#pragma unroll
      for (int n = 0; n < 4; n++) {
        const unsigned short* wp = W3bf + (size_t)(16 * n + lr) * 256 + mc + kb;
        short8 w3v = *(const short8*)wp;
        zacc[0][n] = __builtin_amdgcn_mfma_f32_16x16x32_bf16(ya0, w3v, zacc[0][n], 0, 0, 0);
        zacc[1][n] = __builtin_amdgcn_mfma_f32_16x16x32_bf16(ya1, w3v, zacc[1][n], 0, 0, 0);
      }
    }
  }

  float sp[2][4];
#pragma unroll
  for (int q = 0; q < 2; q++)
#pragma unroll
    for (int r = 0; r < 4; r++) sp[q][r] = 0.f;
#pragma unroll
  for (int n = 0; n < 4; n++) {
    int j = 16 * n + lr;
    float b3v = b3[j], w4v = W4[j];
#pragma unroll
    for (int q = 0; q < 2; q++)
#pragma unroll
      for (int r = 0; r < 4; r++) {
        float z = zacc[q][n][r] + b3v;
        z = z > 0.f ? z : 0.f;
        sp[q][r] += w4v * z;
      }
  }
#pragma unroll
  for (int mask = 1; mask <= 8; mask <<= 1)
#pragma unroll
    for (int q = 0; q < 2; q++)
#pragma unroll
      for (int r = 0; r < 4; r++)
        sp[q][r] += __shfl_xor(sp[q][r], mask, 64);
  float bb4 = b4[0];
  if (lr == 0) {
#pragma unroll
    for (int q = 0; q < 2; q++)
#pragma unroll
      for (int r = 0; r < 4; r++) {
        int v = v0w + 16 * q + lhi * 4 + r;
        float s = 1.f / (1.f + expf(-(sp[q][r] + bb4)));
        wT[((size_t)(b * NC + v)) * NC + u] = s * A_a[u * NC + v];
      }
  }
}

// ---------------------------------------------------------------------------
// Kernel C: a/m einsums + output projections + beta combine, fused. (unchanged)
// ---------------------------------------------------------------------------
__global__ __launch_bounds__(256) void k_out(
    const float* __restrict__ h, const float* __restrict__ wT,
    const float* __restrict__ A_m, const float* __restrict__ W_add,
    const float* __restrict__ b_add, const float* __restrict__ W_mod,
    const float* __restrict__ b_mod, const float* __restrict__ beta1p,
    const float* __restrict__ beta2p, const float* __restrict__ beta3p,
    float* __restrict__ out) {
  int blk = blockIdx.x;
  int b = blk / 80;
  int rest = blk - b * 80;
  int tt = rest >> 2;
  int v0 = (rest & 3) << 5;
  __shared__ float hs[NC][ND];
  __shared__ float WaT[ND][65];
  __shared__ float WmT[ND][65];
  __shared__ float wcol[4][NC];
  __shared__ float amcol[4][NC];
  __shared__ float apre[4][ND];
  __shared__ float mpre[4][ND];
  int t = threadIdx.x;
  const float* hb = h + ((size_t)(b * NT + tt)) * NC * ND;
  for (int i = t; i < NC * ND; i += 256) hs[i >> 6][i & 63] = hb[i];
  for (int i = t; i < ND * ND; i += 256) {
    int d = i >> 6, e = i & 63;
    WaT[e][d] = W_add[i];
    WmT[e][d] = W_mod[i];
  }
  float bb1 = beta1p[0], bb2 = beta2p[0], bb3 = beta3p[0];
  __syncthreads();
  int vi = t >> 6, d = t & 63;
  for (int vo = 0; vo < 8; vo++) {
    for (int i = t; i < 512; i += 256) {
      int vv = i >> 7, uu = i & 127;
      int v = v0 + vo * 4 + vv;
      wcol[vv][uu] = wT[((size_t)(b * NC + v)) * NC + uu];
      amcol[vv][uu] = A_m[uu * NC + v];
    }
    __syncthreads();
    int v = v0 + vo * 4 + vi;
    float asum = 0.f, msum = 0.f;
    for (int uu = 0; uu < NC; uu++) {
      float hv = hs[uu][d];
      asum += wcol[vi][uu] * hv;
      msum += amcol[vi][uu] * hv;
    }
    apre[vi][d] = asum;
    mpre[vi][d] = msum * hs[v][d];
    __syncthreads();
    float accA = b_add[d], accM = b_mod[d];
    for (int e = 0; e < ND; e++) {
      accA += WaT[e][d] * apre[vi][e];
      accM += WmT[e][d] * mpre[vi][e];
    }
    out[(((size_t)(b * NT + tt)) * NC + v) * ND + d] =
        bb1 * hs[v][d] + bb2 * accA + bb3 * accM;
    __syncthreads();
  }
}

// ---------------------------------------------------------------------------
extern "C" void kernel_launch(void* const* d_in, const int* in_sizes, int n_in,
                              void* d_out, int out_size, void* d_ws, size_t ws_size,
                              hipStream_t stream) {
  const float* h     = (const float*)d_in[0];
  const float* W1    = (const float*)d_in[1];
  const float* b1    = (const float*)d_in[2];
  const float* W2    = (const float*)d_in[3];
  const float* b2    = (const float*)d_in[4];
  const float* W3    = (const float*)d_in[5];
  const float* b3    = (const float*)d_in[6];
  const float* W4    = (const float*)d_in[7];
  const float* b4    = (const float*)d_in[8];
  const float* A_a   = (const float*)d_in[9];
  const float* A_m   = (const float*)d_in[10];
  const float* W_add = (const float*)d_in[11];
  const float* b_add = (const float*)d_in[12];
  const float* W_mod = (const float*)d_in[13];
  const float* b_mod = (const float*)d_in[14];
  const float* beta1 = (const float*)d_in[15];
  const float* beta2 = (const float*)d_in[16];
  const float* beta3 = (const float*)d_in[17];
  float* out = (float*)d_out;

  char* ws = (char*)d_ws;
  float* fuv            = (float*)(ws);                    // 512 KB
  float* wT             = (float*)(ws + 512 * 1024);       // 256 KB
  unsigned short* W2bf  = (unsigned short*)(ws + 768 * 1024);   // 64 KB
  unsigned short* W3bf  = (unsigned short*)(ws + 832 * 1024);   // 32 KB
  unsigned short* W1bf  = (unsigned short*)(ws + 864 * 1024);   // 640 KB
  unsigned short* hbf   = (unsigned short*)(ws + 1504 * 1024);  // 1280 KB
  float* part           = (float*)(ws + 2784 * 1024);      // 4 MB

  k_conv<<<252, 256, 0, stream>>>(h, W1, W2, W3, hbf, W1bf, W2bf, W3bf);
  k_fuv_mfma<<<512, 128, 0, stream>>>(hbf, W1bf, part);
  k_fred<<<128, 256, 0, stream>>>(part, fuv);
  k_pair<<<512, 256, 0, stream>>>(fuv, b1, W2bf, b2, W3bf, b3, W4, b4, A_a, wT);
  k_out<<<320, 256, 0, stream>>>(h, wT, A_m, W_add, b_add, W_mod, b_mod,
                                 beta1, beta2, beta3, out);
}

// Round 4
// 58.938 us; speedup vs baseline: 7.9427x; 1.5507x over previous
//
#include <hip/hip_runtime.h>
#include <cmath>

#define NB 4
#define NT 20
#define NC 128
#define ND 64
#define TD 1280   // T*D

typedef short short8 __attribute__((ext_vector_type(8)));
typedef float f32x4 __attribute__((ext_vector_type(4)));

static __device__ __forceinline__ unsigned short f2bf(float f) {
  union { float f; unsigned int u; } v; v.f = f;
  unsigned int r = v.u + 0x7FFFu + ((v.u >> 16) & 1u);
  return (unsigned short)(r >> 16);
}

static __device__ __forceinline__ void conv16(const float* __restrict__ s,
                                              unsigned short* __restrict__ d) {
#pragma unroll
  for (int q = 0; q < 2; q++) {
    float4 f0 = *(const float4*)(s + q * 8);
    float4 f1 = *(const float4*)(s + q * 8 + 4);
    uint4 o;
    o.x = (unsigned)f2bf(f0.x) | ((unsigned)f2bf(f0.y) << 16);
    o.y = (unsigned)f2bf(f0.z) | ((unsigned)f2bf(f0.w) << 16);
    o.z = (unsigned)f2bf(f1.x) | ((unsigned)f2bf(f1.y) << 16);
    o.w = (unsigned)f2bf(f1.z) | ((unsigned)f2bf(f1.w) << 16);
    *(uint4*)(d + q * 8) = o;
  }
}

// ---------------------------------------------------------------------------
// Conversions.  338 blocks x 256 thr.
//   0..159  : h -> hbf (h_flat [b*C+c][t*D+d])
// 160..239  : W1 -> W1bf
// 240..247  : W2 -> W2bf
// 248..251  : W3 -> W3bf
// 252..255  : A_m -> A_mTbf (transposed [v][u])
// 256..257  : W_add/W_mod -> bf16
// 258..337  : h -> hbfT (per-(b,t) transpose [d][u], LDS-tiled)
// ---------------------------------------------------------------------------
__global__ __launch_bounds__(256) void k_conv(
    const float* __restrict__ h, const float* __restrict__ W1,
    const float* __restrict__ W2, const float* __restrict__ W3,
    const float* __restrict__ A_m, const float* __restrict__ W_add,
    const float* __restrict__ W_mod,
    unsigned short* __restrict__ hbf, unsigned short* __restrict__ W1bf,
    unsigned short* __restrict__ W2bf, unsigned short* __restrict__ W3bf,
    unsigned short* __restrict__ A_mTbf, unsigned short* __restrict__ W_addbf,
    unsigned short* __restrict__ W_modbf, unsigned short* __restrict__ hbfT) {
  __shared__ float hsl[128][65];
  int blk = blockIdx.x, tid = threadIdx.x;
  if (blk < 160) {                     // h transpose to h_flat
    int bt = blk >> 1;
    int j = ((blk & 1) << 12) + tid * 16;
    int b = bt / 20;
    int c = j >> 6, d0 = j & 63;
    int t5 = bt - b * 20;
    conv16(h + (size_t)bt * 8192 + j,
           hbf + ((size_t)(b * NC + c)) * TD + t5 * 64 + d0);
  } else if (blk < 240) {              // W1
    size_t i = (size_t)(blk - 160) * 4096 + tid * 16;
    conv16(W1 + i, W1bf + i);
  } else if (blk < 248) {              // W2
    size_t i = (size_t)(blk - 240) * 4096 + tid * 16;
    conv16(W2 + i, W2bf + i);
  } else if (blk < 252) {              // W3
    size_t i = (size_t)(blk - 248) * 4096 + tid * 16;
    conv16(W3 + i, W3bf + i);
  } else if (blk < 256) {              // A_m transpose
    size_t base = (size_t)(blk - 252) * 4096 + tid * 16;
    unsigned short tmp[16];
#pragma unroll
    for (int i2 = 0; i2 < 16; i2++) {
      size_t idx = base + i2;
      int v = (int)(idx >> 7), u = (int)(idx & 127);
      tmp[i2] = f2bf(A_m[(size_t)u * 128 + v]);
    }
    *(uint4*)(A_mTbf + base) = *(uint4*)tmp;
    *(uint4*)(A_mTbf + base + 8) = *(uint4*)(tmp + 8);
  } else if (blk < 258) {              // W_add / W_mod
    size_t i = (size_t)tid * 16;
    if (blk == 256) conv16(W_add + i, W_addbf + i);
    else            conv16(W_mod + i, W_modbf + i);
  } else {                             // hbfT: per-(b,t) [d][u]
    int bt = blk - 258;
    const float* hb = h + (size_t)bt * 8192;
    for (int i = tid; i < 8192; i += 256) hsl[i >> 6][i & 63] = hb[i];
    __syncthreads();
    unsigned short* ob = hbfT + (size_t)bt * 8192;
    for (int i = tid; i < 8192; i += 256) {
      int d = i >> 7, u = i & 127;
      ob[i] = f2bf(hsl[u][d]);         // stride-65 LDS read: conflict-free
    }
  }
}

// ---------------------------------------------------------------------------
// Kernel A (MFMA): fuv = h_flat @ [W1u|W1v]^T.  M=512, N=256, K=1280.
// Grid 256 = 16 Mtiles(32) x 4 Ntiles(64) x 4 Ksplit(320).  128 thr = 2 waves.
// ---------------------------------------------------------------------------
__global__ __launch_bounds__(128) void k_fuv_mfma(
    const unsigned short* __restrict__ hbf,
    const unsigned short* __restrict__ W1bf,
    float* __restrict__ part) {
  int blk = blockIdx.x;
  int mtile = blk & 15;
  int ntile = (blk >> 4) & 3;
  int ks = blk >> 6;
  int t = threadIdx.x;
  int lane = t & 63;
  int w = t >> 6;
  int lr = lane & 15, lhi = lane >> 4;
  int kc0 = ks * 320;
  int row = mtile * 32 + w * 16 + lr;
  const unsigned short* ap = hbf + (size_t)row * TD + kc0 + lhi * 8;
  const unsigned short* bp[4];
#pragma unroll
  for (int nf = 0; nf < 4; nf++) {
    int n = ntile * 64 + nf * 16 + lr;
    bp[nf] = W1bf + (size_t)(n & 127) * (2 * TD) + (n >> 7) * TD + kc0 + lhi * 8;
  }
  f32x4 acc[4];
#pragma unroll
  for (int nf = 0; nf < 4; nf++) acc[nf] = (f32x4){0.f, 0.f, 0.f, 0.f};
#pragma unroll
  for (int kb = 0; kb < 320; kb += 32) {
    short8 a = *(const short8*)(ap + kb);
#pragma unroll
    for (int nf = 0; nf < 4; nf++) {
      short8 bv = *(const short8*)(bp[nf] + kb);
      acc[nf] = __builtin_amdgcn_mfma_f32_16x16x32_bf16(a, bv, acc[nf], 0, 0, 0);
    }
  }
  float* pout = part + (size_t)ks * (512 * 256);
  int m0 = mtile * 32 + w * 16 + lhi * 4;
#pragma unroll
  for (int nf = 0; nf < 4; nf++)
#pragma unroll
    for (int r = 0; r < 4; r++)
      pout[(size_t)(m0 + r) * 256 + ntile * 64 + nf * 16 + lr] = acc[nf][r];
}

// ---------------------------------------------------------------------------
// Reduce split-K partials (4).  Grid 128 x 256, float4/thread.
// ---------------------------------------------------------------------------
__global__ __launch_bounds__(256) void k_fred(
    const float* __restrict__ part, float* __restrict__ fuv) {
  int i = blockIdx.x * 256 + threadIdx.x;
  float4 s = ((const float4*)part)[i];
#pragma unroll
  for (int p = 1; p < 4; p++) {
    float4 v = ((const float4*)part)[i + p * 32768];
    s.x += v.x; s.y += v.y; s.z += v.z; s.w += v.w;
  }
  ((float4*)fuv)[i] = s;
}

// ---------------------------------------------------------------------------
// Kernel B (MFMA): pairwise MLP -> wTbf[b][v][u] (bf16 now).
// ---------------------------------------------------------------------------
__global__ __launch_bounds__(256) void k_pair(
    const float* __restrict__ fuv, const float* __restrict__ b1,
    const unsigned short* __restrict__ W2bf, const float* __restrict__ b2,
    const unsigned short* __restrict__ W3bf, const float* __restrict__ b3,
    const float* __restrict__ W4, const float* __restrict__ b4,
    const float* __restrict__ A_a, unsigned short* __restrict__ wTbf) {
  int blk = blockIdx.x;
  int b = blk >> 7;
  int u = blk & 127;
  __shared__ char x1raw[32768];
  __shared__ char ycraw[4][8192];
  int t = threadIdx.x;
  int lane = t & 63;
  int w = t >> 6;
  const float* fub = fuv + ((size_t)(b * NC + u)) * 256;

  {
    int v = t >> 1;
    int kh2 = (t & 1) << 6;
    const float* fvrow = fuv + ((size_t)(b * NC + v)) * 256 + 128 + kh2;
    const float* fur = fub + kh2;
    const float* b1r = b1 + kh2;
    int sw = (v & 7) << 4;
    int rowbase = v * 256 + kh2 * 2;
    for (int kc = 0; kc < 64; kc += 8) {
      float e[8];
#pragma unroll
      for (int i2 = 0; i2 < 8; i2++) {
        float val = fur[kc + i2] + fvrow[kc + i2] + b1r[kc + i2];
        e[i2] = val > 0.f ? val : 0.f;
      }
      unsigned int pw[4];
#pragma unroll
      for (int i2 = 0; i2 < 4; i2++)
        pw[i2] = (unsigned int)f2bf(e[2 * i2]) |
                 ((unsigned int)f2bf(e[2 * i2 + 1]) << 16);
      *(uint4*)(x1raw + ((rowbase + kc * 2) ^ sw)) =
          make_uint4(pw[0], pw[1], pw[2], pw[3]);
    }
  }
  __syncthreads();

  int v0w = w * 32;
  int lr = lane & 15;
  int lhi = lane >> 4;
  int sw = (lr & 7) << 4;
  char* ycb = ycraw[w];

  f32x4 zacc[2][4];
#pragma unroll
  for (int q = 0; q < 2; q++)
#pragma unroll
    for (int n = 0; n < 4; n++) zacc[q][n] = (f32x4){0.f, 0.f, 0.f, 0.f};

  for (int mc = 0; mc < 256; mc += 64) {
    f32x4 yac[2][4];
#pragma unroll
    for (int q = 0; q < 2; q++)
#pragma unroll
      for (int n = 0; n < 4; n++) yac[q][n] = (f32x4){0.f, 0.f, 0.f, 0.f};
    float b2v[4];
#pragma unroll
    for (int n = 0; n < 4; n++) b2v[n] = b2[mc + 16 * n + lr];

#pragma unroll
    for (int ks = 0; ks < 4; ks++) {
      int kb = ks * 32 + lhi * 8;
      int r0 = (v0w + lr) * 256 + kb * 2;
      short8 a0 = *(const short8*)(x1raw + (r0 ^ sw));
      short8 a1 = *(const short8*)(x1raw + ((r0 + 16 * 256) ^ sw));
#pragma unroll
      for (int n = 0; n < 4; n++) {
        const unsigned short* wp = W2bf + (size_t)(mc + 16 * n + lr) * 128 + kb;
        short8 bfv = *(const short8*)wp;
        yac[0][n] = __builtin_amdgcn_mfma_f32_16x16x32_bf16(a0, bfv, yac[0][n], 0, 0, 0);
        yac[1][n] = __builtin_amdgcn_mfma_f32_16x16x32_bf16(a1, bfv, yac[1][n], 0, 0, 0);
      }
    }
#pragma unroll
    for (int q = 0; q < 2; q++)
#pragma unroll
      for (int n = 0; n < 4; n++) {
        int ml = 16 * n + lr;
#pragma unroll
        for (int r = 0; r < 4; r++) {
          int vl = 16 * q + lhi * 4 + r;
          float yv = yac[q][n][r] + b2v[n];
          yv = yv > 0.f ? yv : 0.f;
          *(unsigned short*)(ycb + ((vl * 128 + ml * 2) ^ ((vl & 7) << 4))) = f2bf(yv);
        }
      }
#pragma unroll
    for (int ks = 0; ks < 2; ks++) {
      int kb = ks * 32 + lhi * 8;
      short8 ya0 = *(const short8*)(ycb + ((lr * 128 + kb * 2) ^ sw));
      short8 ya1 = *(const short8*)(ycb + (((16 + lr) * 128 + kb * 2) ^ sw));
#pragma unroll
      for (int n = 0; n < 4; n++) {
        const unsigned short* wp = W3bf + (size_t)(16 * n + lr) * 256 + mc + kb;
        short8 w3v = *(const short8*)wp;
        zacc[0][n] = __builtin_amdgcn_mfma_f32_16x16x32_bf16(ya0, w3v, zacc[0][n], 0, 0, 0);
        zacc[1][n] = __builtin_amdgcn_mfma_f32_16x16x32_bf16(ya1, w3v, zacc[1][n], 0, 0, 0);
      }
    }
  }

  float sp[2][4];
#pragma unroll
  for (int q = 0; q < 2; q++)
#pragma unroll
    for (int r = 0; r < 4; r++) sp[q][r] = 0.f;
#pragma unroll
  for (int n = 0; n < 4; n++) {
    int j = 16 * n + lr;
    float b3v = b3[j], w4v = W4[j];
#pragma unroll
    for (int q = 0; q < 2; q++)
#pragma unroll
      for (int r = 0; r < 4; r++) {
        float z = zacc[q][n][r] + b3v;
        z = z > 0.f ? z : 0.f;
        sp[q][r] += w4v * z;
      }
  }
#pragma unroll
  for (int mask = 1; mask <= 8; mask <<= 1)
#pragma unroll
    for (int q = 0; q < 2; q++)
#pragma unroll
      for (int r = 0; r < 4; r++)
        sp[q][r] += __shfl_xor(sp[q][r], mask, 64);
  float bb4 = b4[0];
  if (lr == 0) {
#pragma unroll
    for (int q = 0; q < 2; q++)
#pragma unroll
      for (int r = 0; r < 4; r++) {
        int v = v0w + 16 * q + lhi * 4 + r;
        float s = 1.f / (1.f + expf(-(sp[q][r] + bb4)));
        wTbf[((size_t)(b * NC + v)) * NC + u] = f2bf(s * A_a[u * NC + v]);
      }
  }
}

// ---------------------------------------------------------------------------
// Kernel C (MFMA): fused a/m einsums + projections + beta combine.
// Grid 320 = 80 (b,t) x 4 v-quarters.  ONE wave per block, no barriers.
//   stage1: apre[32v][64d] = wT[v][u] @ hT[d][u]^T   (K=128)
//   stage2: mpre[32v][64d] = (A_mT[v][u] @ hT) * h[v][d]
//   stage3: out = b1*h + b2*(apre@W_add^T + b_add) + b3*(mpre@W_mod^T + b_mod)
// apre/mpre staged in wave-private LDS (bf16, XOR-swizzled).
// ---------------------------------------------------------------------------
__global__ __launch_bounds__(64) void k_out_mfma(
    const float* __restrict__ h, const unsigned short* __restrict__ wTbf,
    const unsigned short* __restrict__ A_mTbf,
    const unsigned short* __restrict__ hbfT,
    const unsigned short* __restrict__ W_addbf,
    const unsigned short* __restrict__ W_modbf,
    const float* __restrict__ b_add, const float* __restrict__ b_mod,
    const float* __restrict__ beta1p, const float* __restrict__ beta2p,
    const float* __restrict__ beta3p, float* __restrict__ out) {
  int blk = blockIdx.x;
  int bt = blk >> 2;
  int v0 = (blk & 3) << 5;
  int b = bt / 20;
  __shared__ char apre_l[4096];   // [32 v][64 e] bf16, swizzled
  __shared__ char mpre_l[4096];
  int lane = threadIdx.x;
  int lr = lane & 15, lhi = lane >> 4;

  // ---- stage 1+2: two M=32,N=64,K=128 GEMMs sharing B (hT rows) ----
  f32x4 aacc[2][4], macc[2][4];
#pragma unroll
  for (int q = 0; q < 2; q++)
#pragma unroll
    for (int nf = 0; nf < 4; nf++) {
      aacc[q][nf] = (f32x4){0.f, 0.f, 0.f, 0.f};
      macc[q][nf] = (f32x4){0.f, 0.f, 0.f, 0.f};
    }
  const unsigned short* wrow0 = wTbf + ((size_t)(b * NC + v0 + lr)) * NC + lhi * 8;
  const unsigned short* wrow1 = wrow0 + 16 * NC;
  const unsigned short* arow0 = A_mTbf + (size_t)(v0 + lr) * NC + lhi * 8;
  const unsigned short* arow1 = arow0 + 16 * NC;
  const unsigned short* hTrow = hbfT + (size_t)bt * 8192 + lhi * 8;
#pragma unroll
  for (int kb = 0; kb < 128; kb += 32) {
    short8 aw0 = *(const short8*)(wrow0 + kb);
    short8 aw1 = *(const short8*)(wrow1 + kb);
    short8 am0 = *(const short8*)(arow0 + kb);
    short8 am1 = *(const short8*)(arow1 + kb);
#pragma unroll
    for (int nf = 0; nf < 4; nf++) {
      short8 bv = *(const short8*)(hTrow + (size_t)(nf * 16 + lr) * NC + kb);
      aacc[0][nf] = __builtin_amdgcn_mfma_f32_16x16x32_bf16(aw0, bv, aacc[0][nf], 0, 0, 0);
      aacc[1][nf] = __builtin_amdgcn_mfma_f32_16x16x32_bf16(aw1, bv, aacc[1][nf], 0, 0, 0);
      macc[0][nf] = __builtin_amdgcn_mfma_f32_16x16x32_bf16(am0, bv, macc[0][nf], 0, 0, 0);
      macc[1][nf] = __builtin_amdgcn_mfma_f32_16x16x32_bf16(am1, bv, macc[1][nf], 0, 0, 0);
    }
  }

  // ---- h loads (f32) + elementwise for m + LDS bf16 staging ----
  float hval[2][4][4];
  const float* hbase = h + (size_t)bt * 8192;
#pragma unroll
  for (int q = 0; q < 2; q++)
#pragma unroll
    for (int nf = 0; nf < 4; nf++) {
      int d = nf * 16 + lr;
#pragma unroll
      for (int r = 0; r < 4; r++) {
        int vl = q * 16 + lhi * 4 + r;
        float hv = hbase[(size_t)(v0 + vl) * 64 + d];
        hval[q][nf][r] = hv;
        int byte = (vl * 128 + d * 2) ^ ((vl & 7) << 4);
        *(unsigned short*)(apre_l + byte) = f2bf(aacc[q][nf][r]);
        *(unsigned short*)(mpre_l + byte) = f2bf(macc[q][nf][r] * hv);
      }
    }
  // single wave: LDS visibility via lgkmcnt only, no barrier needed

  // ---- stage 3: two M=32,N=64,K=64 GEMMs ----
  f32x4 oa[2][4], om[2][4];
#pragma unroll
  for (int q = 0; q < 2; q++)
#pragma unroll
    for (int nf = 0; nf < 4; nf++) {
      oa[q][nf] = (f32x4){0.f, 0.f, 0.f, 0.f};
      om[q][nf] = (f32x4){0.f, 0.f, 0.f, 0.f};
    }
  int sw = (lr & 7) << 4;
#pragma unroll
  for (int kb = 0; kb < 64; kb += 32) {
    int off0 = lr * 128 + kb * 2 + lhi * 16;
    short8 pa0 = *(const short8*)(apre_l + (off0 ^ sw));
    short8 pa1 = *(const short8*)(apre_l + ((off0 + 16 * 128) ^ sw));
    short8 pm0 = *(const short8*)(mpre_l + (off0 ^ sw));
    short8 pm1 = *(const short8*)(mpre_l + ((off0 + 16 * 128) ^ sw));
#pragma unroll
    for (int nf = 0; nf < 4; nf++) {
      const unsigned short* wa = W_addbf + (size_t)(nf * 16 + lr) * 64 + kb + lhi * 8;
      const unsigned short* wm = W_modbf + (size_t)(nf * 16 + lr) * 64 + kb + lhi * 8;
      short8 wav = *(const short8*)wa;
      short8 wmv = *(const short8*)wm;
      oa[0][nf] = __builtin_amdgcn_mfma_f32_16x16x32_bf16(pa0, wav, oa[0][nf], 0, 0, 0);
      oa[1][nf] = __builtin_amdgcn_mfma_f32_16x16x32_bf16(pa1, wav, oa[1][nf], 0, 0, 0);
      om[0][nf] = __builtin_amdgcn_mfma_f32_16x16x32_bf16(pm0, wmv, om[0][nf], 0, 0, 0);
      om[1][nf] = __builtin_amdgcn_mfma_f32_16x16x32_bf16(pm1, wmv, om[1][nf], 0, 0, 0);
    }
  }

  float bb1 = beta1p[0], bb2 = beta2p[0], bb3 = beta3p[0];
  float* obase = out + (size_t)bt * 8192 + (size_t)v0 * 64;
#pragma unroll
  for (int q = 0; q < 2; q++)
#pragma unroll
    for (int nf = 0; nf < 4; nf++) {
      int d = nf * 16 + lr;
      float ba = b_add[d], bm = b_mod[d];
#pragma unroll
      for (int r = 0; r < 4; r++) {
        int vl = q * 16 + lhi * 4 + r;
        obase[(size_t)vl * 64 + d] =
            bb1 * hval[q][nf][r] + bb2 * (oa[q][nf][r] + ba) + bb3 * (om[q][nf][r] + bm);
      }
    }
}

// ---------------------------------------------------------------------------
extern "C" void kernel_launch(void* const* d_in, const int* in_sizes, int n_in,
                              void* d_out, int out_size, void* d_ws, size_t ws_size,
                              hipStream_t stream) {
  const float* h     = (const float*)d_in[0];
  const float* W1    = (const float*)d_in[1];
  const float* b1    = (const float*)d_in[2];
  const float* W2    = (const float*)d_in[3];
  const float* b2    = (const float*)d_in[4];
  const float* W3    = (const float*)d_in[5];
  const float* b3    = (const float*)d_in[6];
  const float* W4    = (const float*)d_in[7];
  const float* b4    = (const float*)d_in[8];
  const float* A_a   = (const float*)d_in[9];
  const float* A_m   = (const float*)d_in[10];
  const float* W_add = (const float*)d_in[11];
  const float* b_add = (const float*)d_in[12];
  const float* W_mod = (const float*)d_in[13];
  const float* b_mod = (const float*)d_in[14];
  const float* beta1 = (const float*)d_in[15];
  const float* beta2 = (const float*)d_in[16];
  const float* beta3 = (const float*)d_in[17];
  float* out = (float*)d_out;

  char* ws = (char*)d_ws;
  float* fuv            = (float*)(ws);                         // 512 KB
  unsigned short* wTbf  = (unsigned short*)(ws + 512 * 1024);   // 128 KB
  unsigned short* A_mTbf= (unsigned short*)(ws + 640 * 1024);   // 32 KB
  unsigned short* W_addbf=(unsigned short*)(ws + 672 * 1024);   // 8 KB
  unsigned short* W_modbf=(unsigned short*)(ws + 680 * 1024);   // 8 KB
  unsigned short* W2bf  = (unsigned short*)(ws + 688 * 1024);   // 64 KB
  unsigned short* W3bf  = (unsigned short*)(ws + 752 * 1024);   // 32 KB
  unsigned short* W1bf  = (unsigned short*)(ws + 784 * 1024);   // 640 KB
  unsigned short* hbf   = (unsigned short*)(ws + 1424 * 1024);  // 1280 KB
  unsigned short* hbfT  = (unsigned short*)(ws + 2704 * 1024);  // 1280 KB
  float* part           = (float*)(ws + 3984 * 1024);           // 2048 KB

  k_conv<<<338, 256, 0, stream>>>(h, W1, W2, W3, A_m, W_add, W_mod,
                                  hbf, W1bf, W2bf, W3bf, A_mTbf, W_addbf,
                                  W_modbf, hbfT);
  k_fuv_mfma<<<256, 128, 0, stream>>>(hbf, W1bf, part);
  k_fred<<<128, 256, 0, stream>>>(part, fuv);
  k_pair<<<512, 256, 0, stream>>>(fuv, b1, W2bf, b2, W3bf, b3, W4, b4, A_a, wTbf);
  k_out_mfma<<<320, 64, 0, stream>>>(h, wTbf, A_mTbf, hbfT, W_addbf, W_modbf,
                                     b_add, b_mod, beta1, beta2, beta3, out);
}